// Round 6
// baseline (112989.673 us; speedup 1.0000x reference)
//
#include <hip/hip_runtime.h>
#include <math.h>

// Round 6: R4 barrier restored (empirically best), R5's LDS padding kept.
// All big GEMMs (x-gates, he_pre, ysp) -> bf16 MFMA 16x16x32 with on-the-fly
// fp32->bf16 conversion (no extra workspace). Output GEMM (W_yy) stays fp32.

#define T_    800
#define B_    16
#define FEAT_ 120
#define H_    512
#define H2_   1024
#define H4_   2048
#define CC_   5000
#define NL_   100
#define CH_   50

typedef __attribute__((ext_vector_type(8))) short bf16x8;
typedef __attribute__((ext_vector_type(4))) float f32x4;

// ---------------- coherent access helpers ----------------
__device__ __forceinline__ void coh_store_f32(float* p, float v) {
  asm volatile("global_store_dword %0, %1, off sc0 sc1"
               :: "v"(p), "v"(v) : "memory");
}

__device__ __forceinline__ void coh_load8_f4(
    const float4* p0, const float4* p1, const float4* p2, const float4* p3,
    const float4* p4, const float4* p5, const float4* p6, const float4* p7,
    float4* o)
{
  asm volatile(
      "global_load_dwordx4 %0, %8, off sc0 sc1\n\t"
      "global_load_dwordx4 %1, %9, off sc0 sc1\n\t"
      "global_load_dwordx4 %2, %10, off sc0 sc1\n\t"
      "global_load_dwordx4 %3, %11, off sc0 sc1\n\t"
      "global_load_dwordx4 %4, %12, off sc0 sc1\n\t"
      "global_load_dwordx4 %5, %13, off sc0 sc1\n\t"
      "global_load_dwordx4 %6, %14, off sc0 sc1\n\t"
      "global_load_dwordx4 %7, %15, off sc0 sc1\n\t"
      "s_waitcnt vmcnt(0)"
      : "=&v"(o[0]), "=&v"(o[1]), "=&v"(o[2]), "=&v"(o[3]),
        "=&v"(o[4]), "=&v"(o[5]), "=&v"(o[6]), "=&v"(o[7])
      : "v"(p0), "v"(p1), "v"(p2), "v"(p3), "v"(p4), "v"(p5), "v"(p6), "v"(p7)
      : "memory");
}

// ---------------- bf16 MFMA GEMM: C = A @ W^T + bias ----------------
// A: [M][K] fp32, W: [N][K] fp32, C: [M][ldc] fp32. K % 4 == 0. N % 128 == 0.
#define GBM 128
#define GBN 128
#define GBK 32
#define LDT 40   // LDS row stride in ushorts (32 data + 8 pad; 80B, 16B-aligned)

__device__ __forceinline__ unsigned short f2bf(float f) {
  unsigned u = __builtin_bit_cast(unsigned, f);
  u += 0x7FFFu + ((u >> 16) & 1u);   // RNE
  return (unsigned short)(u >> 16);
}

__device__ __forceinline__ void mfma_gemm_body(
    const float* __restrict__ A, const float* __restrict__ W,
    const float* __restrict__ bias, float* __restrict__ C,
    int M, int N, int K, int ldc)
{
  __shared__ unsigned short As[GBM * LDT];
  __shared__ unsigned short Ws[GBN * LDT];
  const int tid = threadIdx.x;
  const int row0 = blockIdx.y * GBM, col0 = blockIdx.x * GBN;
  const int lane = tid & 63, w = tid >> 6;
  const int wr = w >> 1, wc = w & 1;
  const int lm = lane & 15, lk8 = (lane >> 4) * 8;

  f32x4 acc[4][4];
#pragma unroll
  for (int i = 0; i < 4; i++)
#pragma unroll
    for (int j = 0; j < 4; j++) acc[i][j] = (f32x4)(0.f);

  const int sr = tid >> 1, skh = (tid & 1) * 16;   // staging: row, k-half

  for (int kt = 0; kt < K; kt += GBK) {
    // ---- stage A and W tiles (fp32 -> bf16) ----
    {
      const int ar = row0 + sr;
      const int wrow = col0 + sr;
      unsigned short abuf[16], wbuf[16];
#pragma unroll
      for (int q = 0; q < 4; q++) {
        const int k0 = kt + skh + q * 4;
        float4 av = make_float4(0.f, 0.f, 0.f, 0.f);
        float4 wv = make_float4(0.f, 0.f, 0.f, 0.f);
        if (k0 + 4 <= K) {
          if (ar < M)   av = *(const float4*)(A + (size_t)ar * K + k0);
          if (wrow < N) wv = *(const float4*)(W + (size_t)wrow * K + k0);
        }
        abuf[q*4+0] = f2bf(av.x); abuf[q*4+1] = f2bf(av.y);
        abuf[q*4+2] = f2bf(av.z); abuf[q*4+3] = f2bf(av.w);
        wbuf[q*4+0] = f2bf(wv.x); wbuf[q*4+1] = f2bf(wv.y);
        wbuf[q*4+2] = f2bf(wv.z); wbuf[q*4+3] = f2bf(wv.w);
      }
      __syncthreads();
      *(uint4*)(As + sr * LDT + skh)     = *(uint4*)(abuf);
      *(uint4*)(As + sr * LDT + skh + 8) = *(uint4*)(abuf + 8);
      *(uint4*)(Ws + sr * LDT + skh)     = *(uint4*)(wbuf);
      *(uint4*)(Ws + sr * LDT + skh + 8) = *(uint4*)(wbuf + 8);
      __syncthreads();
    }
    // ---- fragments + MFMA ----
    bf16x8 af[4], bf[4];
#pragma unroll
    for (int mi = 0; mi < 4; mi++)
      af[mi] = *(const bf16x8*)(As + (wr * 64 + mi * 16 + lm) * LDT + lk8);
#pragma unroll
    for (int ni = 0; ni < 4; ni++)
      bf[ni] = *(const bf16x8*)(Ws + (wc * 64 + ni * 16 + lm) * LDT + lk8);
#pragma unroll
    for (int mi = 0; mi < 4; mi++)
#pragma unroll
      for (int ni = 0; ni < 4; ni++)
        acc[mi][ni] = __builtin_amdgcn_mfma_f32_16x16x32_bf16(
            af[mi], bf[ni], acc[mi][ni], 0, 0, 0);
  }

  // ---- epilogue: D[row][col], row=(lane>>4)*4+reg, col=lane&15 (m89) ----
#pragma unroll
  for (int mi = 0; mi < 4; mi++) {
#pragma unroll
    for (int reg = 0; reg < 4; reg++) {
      const int row = row0 + wr * 64 + mi * 16 + (lane >> 4) * 4 + reg;
      if (row < M) {
        float* crow = C + (size_t)row * ldc;
#pragma unroll
        for (int ni = 0; ni < 4; ni++) {
          const int col = col0 + wc * 64 + ni * 16 + lm;
          crow[col] = acc[mi][ni][reg] + (bias ? bias[col] : 0.f);
        }
      }
    }
  }
}

__global__ __launch_bounds__(256) void gemm_mfma(
    const float* __restrict__ A, const float* __restrict__ W,
    const float* __restrict__ bias, float* __restrict__ C,
    int M, int N, int K, int ldc)
{
  mfma_gemm_body(A, W, bias, C, M, N, K, ldc);
}

__global__ __launch_bounds__(256) void gemm_mfma_dual(
    const float* __restrict__ A0, const float* __restrict__ W0,
    const float* __restrict__ b0, float* __restrict__ C0,
    const float* __restrict__ A1, const float* __restrict__ W1,
    const float* __restrict__ b1, float* __restrict__ C1,
    int M, int N, int K, int ldc)
{
  if (blockIdx.z == 0) mfma_gemm_body(A0, W0, b0, C0, M, N, K, ldc);
  else                 mfma_gemm_body(A1, W1, b1, C1, M, N, K, ldc);
}

__global__ __launch_bounds__(256) void transpose_x(
    const float* __restrict__ x, float* __restrict__ xt)
{
  const int i = blockIdx.x * 256 + threadIdx.x;
  if (i >= T_ * B_ * FEAT_) return;
  const int f = i % FEAT_;
  const int r = i / FEAT_;
  const int b = r % B_;
  const int t = r / B_;
  xt[i] = x[((long)b * T_ + t) * FEAT_ + f];
}

// ---------------- persistent chunk LSTM (R4 barrier + R5 padding) ----------
__device__ __forceinline__ void grid_barrier(unsigned* cnt, unsigned* gen,
                                             unsigned nwg)
{
  __syncthreads();
  if (threadIdx.x == 0) {
    __threadfence();
    unsigned g = __hip_atomic_load(gen, __ATOMIC_RELAXED, __HIP_MEMORY_SCOPE_AGENT);
    unsigned a = __hip_atomic_fetch_add(cnt, 1u, __ATOMIC_ACQ_REL,
                                        __HIP_MEMORY_SCOPE_AGENT);
    if (a == nwg - 1) {
      __hip_atomic_store(cnt, 0u, __ATOMIC_RELAXED, __HIP_MEMORY_SCOPE_AGENT);
      __hip_atomic_store(gen, g + 1u, __ATOMIC_RELEASE, __HIP_MEMORY_SCOPE_AGENT);
    } else {
      long tries = 0;
      while (__hip_atomic_load(gen, __ATOMIC_ACQUIRE,
                               __HIP_MEMORY_SCOPE_AGENT) == g) {
        __builtin_amdgcn_s_sleep(4);
        if (++tries > (3L << 21)) break;  // fail loud, never hang
      }
    }
  }
  __syncthreads();
}

#define HP_ 516   // padded h row

__global__ __launch_bounds__(256, 1) void lstm_chunk(
    const float* __restrict__ gxF,   // [CH][B][4H] fwd x-gates (+bias)
    const float* __restrict__ gxB,   // [CH][B][4H] bwd x-gates (local t = CH-1-ls)
    float* __restrict__ hg0,         // [2][B][H] h for even steps
    float* __restrict__ hg1,         // [2][B][H] h for odd steps
    float* __restrict__ cg,          // [2][B][H] c carry
    float* __restrict__ outb,        // [T][B][2H]
    const float* __restrict__ WhhF, const float* __restrict__ WhhB,
    const int* __restrict__ lengths, int s0, unsigned* __restrict__ bar)
{
  __shared__ float h_lds[16 * HP_];
  __shared__ float gl[16 * 16];
  __shared__ float c_l[64];
  __shared__ int   len_l[16];
  __shared__ float pad[12 * 1024];    // residency pad -> 1 WG/CU

  const int wg  = blockIdx.x;
  const int dir = wg >> 7;
  const int jbase = (wg & 127) * 4;
  const int tid = threadIdx.x;
  const int ks = tid & 15, bq = (tid >> 4) & 3, rq = tid >> 6;

  if (tid < 16) len_l[tid] = lengths[tid];
  if (tid < 64) {
    const int b = tid & 15, j = tid >> 4;
    c_l[tid] = cg[(dir * B_ + b) * H_ + jbase + j];
    if (tid == 0) pad[0] = (float)len_l[0];
  }

  const float* Whh = dir ? WhhB : WhhF;
  float4 wreg[4][8];
#pragma unroll
  for (int r = 0; r < 4; r++) {
    const float* wrow = Whh + (size_t)(rq * 512 + jbase + r) * 512;
#pragma unroll
    for (int i = 0; i < 8; i++)
      wreg[r][i] = *(const float4*)(wrow + ks * 4 + i * 64);
  }
  __syncthreads();

  unsigned* bcnt = bar + dir * 64;
  unsigned* bgen = bar + dir * 64 + 16;

  for (int ls = 0; ls < CH_; ls++) {
    const int s = s0 + ls;
    {
      const float4* hb4 = (const float4*)(((s & 1) ? hg1 : hg0) + dir * (B_ * H_));
      float4 hv[8];
      coh_load8_f4(hb4 + tid,        hb4 + tid + 256,  hb4 + tid + 512,
                   hb4 + tid + 768,  hb4 + tid + 1024, hb4 + tid + 1280,
                   hb4 + tid + 1536, hb4 + tid + 1792, hv);
#pragma unroll
      for (int q = 0; q < 8; q++) {
        const int flat = tid + q * 256;
        const int row = flat >> 7, c4 = flat & 127;
        *(float4*)&h_lds[row * HP_ + c4 * 4] = hv[q];
      }
    }
    __syncthreads();

    float acc[4][4];
#pragma unroll
    for (int r = 0; r < 4; r++)
#pragma unroll
      for (int bi = 0; bi < 4; bi++) acc[r][bi] = 0.f;
#pragma unroll
    for (int i = 0; i < 8; i++) {
      float4 h4[4];
#pragma unroll
      for (int bi = 0; bi < 4; bi++)
        h4[bi] = *(const float4*)&h_lds[(bq * 4 + bi) * HP_ + ks * 4 + i * 64];
#pragma unroll
      for (int r = 0; r < 4; r++) {
        const float4 w4 = wreg[r][i];
#pragma unroll
        for (int bi = 0; bi < 4; bi++) {
          acc[r][bi] = fmaf(w4.x, h4[bi].x, acc[r][bi]);
          acc[r][bi] = fmaf(w4.y, h4[bi].y, acc[r][bi]);
          acc[r][bi] = fmaf(w4.z, h4[bi].z, acc[r][bi]);
          acc[r][bi] = fmaf(w4.w, h4[bi].w, acc[r][bi]);
        }
      }
    }
#pragma unroll
    for (int off = 1; off < 16; off <<= 1)
#pragma unroll
      for (int r = 0; r < 4; r++)
#pragma unroll
        for (int bi = 0; bi < 4; bi++)
          acc[r][bi] += __shfl_xor(acc[r][bi], off);
    if (ks == 0) {
#pragma unroll
      for (int r = 0; r < 4; r++)
#pragma unroll
        for (int bi = 0; bi < 4; bi++)
          gl[(rq * 4 + r) * 16 + bq * 4 + bi] = acc[r][bi];
    }
    __syncthreads();

    if (tid < 64) {
      const int b = tid & 15, j = tid >> 4;
      const int t = dir ? (T_ - 1 - s) : s;
      const int lt = dir ? (CH_ - 1 - ls) : ls;
      const float* gx = (dir ? gxB : gxF) + ((size_t)lt * B_ + b) * H4_ + jbase + j;
      const float gi = gl[(0 + j) * 16 + b]  + gx[0];
      const float gf = gl[(4 + j) * 16 + b]  + gx[512];
      const float gc = gl[(8 + j) * 16 + b]  + gx[1024];
      const float go = gl[(12 + j) * 16 + b] + gx[1536];
      const float iv = 1.f / (1.f + expf(-gi));
      const float fv = 1.f / (1.f + expf(-gf));
      const float gv = tanhf(gc);
      const float ov = 1.f / (1.f + expf(-go));
      const float c_old = c_l[tid];
      const float h_old = h_lds[b * HP_ + jbase + j];
      const float cn = fv * c_old + iv * gv;
      const float hn = ov * tanhf(cn);
      const bool mk = t < len_l[b];
      c_l[tid] = mk ? cn : c_old;
      float* hdst = ((s & 1) ? hg0 : hg1) + dir * (B_ * H_);
      coh_store_f32(&hdst[b * 512 + jbase + j], mk ? hn : h_old);
      outb[((size_t)t * B_ + b) * H2_ + dir * H_ + jbase + j] = mk ? hn : 0.f;
    }
    if (ls != CH_ - 1) grid_barrier(bcnt, bgen, 128);
    if (len_l[0] == -12345) outb[0] = pad[0];
  }
  if (tid < 64)
    cg[(dir * B_ + (tid & 15)) * H_ + jbase + (tid >> 4)] = c_l[tid];
}

// ---------------- decoder kernels (unchanged) ----------------
template <int ACT>
__global__ __launch_bounds__(256) void dotbn(
    const float* __restrict__ S1, const float* __restrict__ W1, int K1,
    const float* __restrict__ S2, const float* __restrict__ W2, int K2,
    const float* __restrict__ pre, int preStride,
    const float* __restrict__ bias,
    float* __restrict__ outp, int outStride, int N)
{
  const int idx = blockIdx.x * 256 + threadIdx.x;
  if (idx >= N * B_) return;
  const int b = idx & 15, n = idx >> 4;
  float acc = bias ? bias[n] : 0.f;
  if (pre) acc += pre[(long)b * preStride + n];
  {
    const float* s = S1 + (long)b * K1;
    const float* w = W1 + (long)n * K1;
#pragma unroll 4
    for (int k = 0; k < K1; k += 4) {
      float4 sv = *(const float4*)(s + k);
      float4 wv = *(const float4*)(w + k);
      acc = fmaf(sv.x, wv.x, acc); acc = fmaf(sv.y, wv.y, acc);
      acc = fmaf(sv.z, wv.z, acc); acc = fmaf(sv.w, wv.w, acc);
    }
  }
  if (S2) {
    const float* s = S2 + (long)b * K2;
    const float* w = W2 + (long)n * K2;
#pragma unroll 4
    for (int k = 0; k < K2; k += 4) {
      float4 sv = *(const float4*)(s + k);
      float4 wv = *(const float4*)(w + k);
      acc = fmaf(sv.x, wv.x, acc); acc = fmaf(sv.y, wv.y, acc);
      acc = fmaf(sv.z, wv.z, acc); acc = fmaf(sv.w, wv.w, acc);
    }
  }
  if (ACT == 1) acc = tanhf(acc);
  outp[(long)b * outStride + n] = acc;
}

__global__ __launch_bounds__(256) void dec_conv(
    const float* __restrict__ alpha, const float* __restrict__ cw,
    float* __restrict__ conv)
{
  const int idx = blockIdx.x * 256 + threadIdx.x;
  if (idx >= B_ * 10 * T_) return;
  const int t = idx % T_;
  const int f = (idx / T_) % 10;
  const int b = idx / (10 * T_);
  const float* a = alpha + b * T_;
  const float* w = cw + f * 100;
  float acc = 0.f;
  const int k0 = (50 - t) > 0 ? (50 - t) : 0;
  const int k1 = (T_ + 50 - t) < 100 ? (T_ + 50 - t) : 100;
  for (int k = k0; k < k1; k++) acc = fmaf(a[t + k - 50], w[k], acc);
  conv[idx] = acc;
}

__global__ __launch_bounds__(256) void att_e(
    const float* __restrict__ se, const float* __restrict__ he,
    const float* __restrict__ conv, const float* __restrict__ W_fe,
    const float* __restrict__ W_ee, float* __restrict__ e)
{
  __shared__ float wfe[10240];
  __shared__ float ses[1024];
  __shared__ float wee[1024];
  __shared__ float red[4];
  const int wg = blockIdx.x;
  const int b = wg / 50, t0 = (wg % 50) * 16;
  const int tid = threadIdx.x;
  for (int i = tid; i < 10240; i += 256) wfe[i] = W_fe[i];
  for (int i = tid; i < 1024; i += 256) {
    ses[i] = se[b * H2_ + i];
    wee[i] = W_ee[i];
  }
  __syncthreads();
  for (int tt = 0; tt < 16; tt++) {
    const int t = t0 + tt;
    float cv[10];
#pragma unroll
    for (int f = 0; f < 10; f++) cv[f] = conv[(b * 10 + f) * T_ + t];
    const float* hrow = he + ((long)t * B_ + b) * H2_;
    float part = 0.f;
#pragma unroll
    for (int q = 0; q < 4; q++) {
      const int d = tid + q * 256;
      float loc = 0.f;
      const float* wf = &wfe[d * 10];
#pragma unroll
      for (int f = 0; f < 10; f++) loc = fmaf(cv[f], wf[f], loc);
      const float val = tanhf(ses[d] + hrow[d] + loc);
      part = fmaf(val, wee[d], part);
    }
#pragma unroll
    for (int off = 32; off; off >>= 1) part += __shfl_down(part, off);
    if ((tid & 63) == 0) red[tid >> 6] = part;
    __syncthreads();
    if (tid == 0) e[b * T_ + t] = red[0] + red[1] + red[2] + red[3];
    __syncthreads();
  }
}

__global__ __launch_bounds__(256) void att_softmax(
    const float* __restrict__ e, const int* __restrict__ lengths,
    float* __restrict__ alpha)
{
  __shared__ float red[4];
  __shared__ float bc, bc2;
  const int b = blockIdx.x, tid = threadIdx.x;
  const int len = lengths[b];
  float v[4];
  float mx = -1e30f;
#pragma unroll
  for (int q = 0; q < 4; q++) {
    const int t = tid + q * 256;
    v[q] = (t < T_) ? e[b * T_ + t] : -1e30f;
    mx = fmaxf(mx, v[q]);
  }
#pragma unroll
  for (int off = 32; off; off >>= 1) mx = fmaxf(mx, __shfl_down(mx, off));
  if ((tid & 63) == 0) red[tid >> 6] = mx;
  __syncthreads();
  if (tid == 0) bc = fmaxf(fmaxf(red[0], red[1]), fmaxf(red[2], red[3]));
  __syncthreads();
  const float m = bc;
  float ex[4];
  float s = 0.f;
#pragma unroll
  for (int q = 0; q < 4; q++) {
    const int t = tid + q * 256;
    ex[q] = (t < T_ && t < len) ? expf(v[q] - m) : 0.f;
    s += ex[q];
  }
#pragma unroll
  for (int off = 32; off; off >>= 1) s += __shfl_down(s, off);
  __syncthreads();
  if ((tid & 63) == 0) red[tid >> 6] = s;
  __syncthreads();
  if (tid == 0) bc2 = red[0] + red[1] + red[2] + red[3];
  __syncthreads();
  const float inv = 1.f / bc2;
#pragma unroll
  for (int q = 0; q < 4; q++) {
    const int t = tid + q * 256;
    if (t < T_) alpha[b * T_ + t] = ex[q] * inv;
  }
}

__global__ __launch_bounds__(256) void att_g(
    const float* __restrict__ alpha, const float* __restrict__ hb,
    float* __restrict__ g)
{
  const int idx = blockIdx.x * 256 + threadIdx.x;
  const int d = idx & (H2_ - 1), b = idx >> 10;
  const float* ab = alpha + b * T_;
  float acc = 0.f;
#pragma unroll 8
  for (int t = 0; t < T_; t++)
    acc = fmaf(ab[t], hb[((long)t * B_ + b) * H2_ + d], acc);
  g[idx] = acc;
}

__global__ __launch_bounds__(256) void dec_update(
    const float* __restrict__ rec, float* __restrict__ s, float* __restrict__ c)
{
  const int idx = blockIdx.x * 256 + threadIdx.x;
  if (idx >= B_ * H_) return;
  const int jj = idx & 511, b = idx >> 9;
  const float* r = rec + b * H4_;
  const float gi = r[jj], gf = r[jj + 512], gc = r[jj + 1024], go = r[jj + 1536];
  const float iv = tanhf(gi * 0.5f) * 0.5f + 0.5f;
  const float fv = tanhf(gf * 0.5f) * 0.5f + 0.5f;
  const float cg = tanhf(gc);
  const float ov = tanhf(go * 0.5f) * 0.5f + 0.5f;
  const float cn = fv * c[idx] + iv * cg;
  const float sn = ov * tanhf(cn);
  c[idx] = cn;
  s[idx] = sn;
}

extern "C" void kernel_launch(void* const* d_in, const int* in_sizes, int n_in,
                              void* d_out, int out_size, void* d_ws, size_t ws_size,
                              hipStream_t stream)
{
  const float* x       = (const float*)d_in[0];
  const int*   lengths = (const int*)  d_in[1];
  const float* target  = (const float*)d_in[2];
  const float* Wih0    = (const float*)d_in[3];
  const float* Whh0    = (const float*)d_in[4];
  const float* b0      = (const float*)d_in[5];
  const float* WihL    = (const float*)d_in[6];
  const float* WhhL    = (const float*)d_in[7];
  const float* bL      = (const float*)d_in[8];
  const float* W_se    = (const float*)d_in[9];
  const float* W_he    = (const float*)d_in[10];
  const float* b_he    = (const float*)d_in[11];
  const float* W_ee    = (const float*)d_in[12];
  const float* conv_w  = (const float*)d_in[13];
  const float* W_fe    = (const float*)d_in[14];
  const float* W_sy    = (const float*)d_in[15];
  const float* W_gy    = (const float*)d_in[16];
  const float* b_gy    = (const float*)d_in[17];
  const float* W_yy    = (const float*)d_in[18];
  const float* b_yy    = (const float*)d_in[19];
  const float* W_ys    = (const float*)d_in[20];
  const float* W_ss    = (const float*)d_in[21];
  const float* W_gs    = (const float*)d_in[22];
  const float* b_gs    = (const float*)d_in[23];
  float* out = (float*)d_out;

  // ---- workspace layout (~119.3 MB) ----
  float* bufA = (float*)d_ws;
  float* bufB = bufA + (size_t)T_ * B_ * H2_;
  float* gxc  = bufB + (size_t)T_ * B_ * H2_;
  float* gxcF = gxc;
  float* gxcB = gxc + (size_t)CH_ * B_ * H4_;
  float* he   = bufB;
  float* ysp  = gxc;
  float* st   = gxc + (size_t)2 * CH_ * B_ * H4_;
  float* hg0  = st;
  float* hg1  = hg0 + 2 * B_ * H_;
  float* cg   = hg1 + 2 * B_ * H_;
  float* sdec = cg + 2 * B_ * H_;
  float* cdec = sdec + B_ * H_;
  float* alpha= cdec + B_ * H_;
  float* conv = alpha + B_ * T_;
  float* ebuf = conv + B_ * 10 * T_;
  float* sebuf= ebuf + B_ * T_;
  float* gvec = sebuf + B_ * H2_;
  float* zvec = gvec + B_ * H2_;
  float* rec  = zvec + B_ * H_;
  unsigned* bar = (unsigned*)(rec + B_ * H4_ + 32);

  // ---- encoder ----
  transpose_x<<<(T_ * B_ * FEAT_ + 255) / 256, 256, 0, stream>>>(x, bufA);

  float* inb  = bufA;
  float* outb = bufB;
  for (int l = 0; l < 4; l++) {
    const int Kin = (l == 0) ? FEAT_ : H2_;
    const float *WihF, *WihB, *WhhF, *WhhB, *bF, *bB;
    if (l == 0) {
      WihF = Wih0;                 WihB = Wih0 + (size_t)H4_ * FEAT_;
      WhhF = Whh0;                 WhhB = Whh0 + (size_t)H4_ * H_;
      bF = b0;                     bB = b0 + H4_;
    } else {
      const size_t o = (size_t)(l - 1) * 2;
      WihF = WihL + o * H4_ * H2_; WihB = WihF + (size_t)H4_ * H2_;
      WhhF = WhhL + o * H4_ * H_;  WhhB = WhhF + (size_t)H4_ * H_;
      bF = bL + o * H4_;           bB = bF + H4_;
    }
    (void)hipMemsetAsync(hg0, 0, (size_t)3 * 2 * B_ * H_ * sizeof(float), stream);
    dim3 gg(H4_ / GBN, (CH_ * B_ + GBM - 1) / GBM, 2);  // (16, 7, 2)
    for (int c = 0; c < T_ / CH_; c++) {
      const int s0 = c * CH_;
      gemm_mfma_dual<<<gg, 256, 0, stream>>>(
          inb + (size_t)s0 * B_ * Kin, WihF, bF, gxcF,
          inb + (size_t)(T_ - s0 - CH_) * B_ * Kin, WihB, bB, gxcB,
          CH_ * B_, H4_, Kin, H4_);
      (void)hipMemsetAsync(bar, 0, 512, stream);
      lstm_chunk<<<256, 256, 0, stream>>>(gxcF, gxcB, hg0, hg1, cg, outb,
                                          WhhF, WhhB, lengths, s0, bar);
    }
    float* tmp = inb; inb = outb; outb = tmp;
  }
  float* hb = inb;  // final encoder output = bufA

  // ---- decoder precompute (bf16 MFMA) ----
  {
    dim3 ghe(H2_ / GBN, (T_ * B_) / GBM);  // (8, 100)
    gemm_mfma<<<ghe, 256, 0, stream>>>(hb, W_he, b_he, he, T_ * B_, H2_, H2_, H2_);
    dim3 gys(H4_ / GBN, (B_ * NL_ + GBM - 1) / GBM);  // (16, 13)
    gemm_mfma<<<gys, 256, 0, stream>>>(target, W_ys, b_gs, ysp, B_ * NL_, H4_, CC_, H4_);
  }
  (void)hipMemsetAsync(sdec, 0, (size_t)(2 * B_ * H_ + B_ * T_) * sizeof(float), stream);

  // ---- decoder steps ----
  for (int step = 0; step < NL_; step++) {
    dec_conv<<<(B_ * 10 * T_ + 255) / 256, 256, 0, stream>>>(alpha, conv_w, conv);
    dotbn<0><<<(B_ * H2_) / 256, 256, 0, stream>>>(
        sdec, W_se, H_, nullptr, nullptr, 0, nullptr, 0, nullptr, sebuf, H2_, H2_);
    att_e<<<800, 256, 0, stream>>>(sebuf, he, conv, W_fe, W_ee, ebuf);
    att_softmax<<<B_, 256, 0, stream>>>(ebuf, lengths, alpha);
    att_g<<<(B_ * H2_) / 256, 256, 0, stream>>>(alpha, hb, gvec);
    dotbn<1><<<(B_ * H_) / 256, 256, 0, stream>>>(
        gvec, W_gy, H2_, sdec, W_sy, H_, nullptr, 0, b_gy, zvec, H_, H_);
    dotbn<0><<<(B_ * CC_ + 255) / 256, 256, 0, stream>>>(
        zvec, W_yy, H_, nullptr, nullptr, 0, nullptr, 0, b_yy,
        out + (size_t)step * CC_, NL_ * CC_, CC_);
    dotbn<0><<<(B_ * H4_) / 256, 256, 0, stream>>>(
        sdec, W_ss, H_, gvec, W_gs, H2_, ysp + (size_t)step * H4_, NL_ * H4_,
        nullptr, rec, H4_, H4_);
    dec_update<<<(B_ * H_) / 256, 256, 0, stream>>>(rec, sdec, cdec);
  }
}

// Round 7
// 61089.728 us; speedup vs baseline: 1.8496x; 1.8496x over previous
//
#include <hip/hip_runtime.h>
#include <math.h>

// Round 7: group-split persistent LSTM.
//   - 16 groups x 16 WGs; group = (dir, batch-pair). Batch rows are
//     independent chains -> barrier fan-in drops 128 -> 16.
//   - per-WG: 128 gate-rows, weights in 256 VGPRs/thread (launch_bounds(256,1)).
//   - per-step gather: 4KB (1 dwordx4/thread) via sc0/sc1 coherent loads.
//   - barrier: R4's relaxed monotonic fetch_add + vmcnt drain (the 61ms
//     variant; R6 accidentally used R3's fence-heavy one -> +50ms).
//   - bf16 MFMA GEMMs kept from R6 (validated: absmax 0.0117).

#define T_    800
#define B_    16
#define FEAT_ 120
#define H_    512
#define H2_   1024
#define H4_   2048
#define CC_   5000
#define NL_   100
#define CH_   50

typedef __attribute__((ext_vector_type(8))) short bf16x8;
typedef __attribute__((ext_vector_type(4))) float f32x4;

// ---------------- coherent helpers ----------------
__device__ __forceinline__ void coh_store_f32(float* p, float v) {
  asm volatile("global_store_dword %0, %1, off sc0 sc1"
               :: "v"(p), "v"(v) : "memory");
}
__device__ __forceinline__ float4 coh_load_f4(const float* p) {
  float4 v;
  asm volatile("global_load_dwordx4 %0, %1, off sc0 sc1\n\t"
               "s_waitcnt vmcnt(0)"
               : "=&v"(v) : "v"(p) : "memory");
  return v;
}

// ---------------- bf16 MFMA GEMM: C = A @ W^T + bias (from R6) ----------
#define GBM 128
#define GBN 128
#define GBK 32
#define LDT 40

__device__ __forceinline__ unsigned short f2bf(float f) {
  unsigned u = __builtin_bit_cast(unsigned, f);
  u += 0x7FFFu + ((u >> 16) & 1u);
  return (unsigned short)(u >> 16);
}

__device__ __forceinline__ void mfma_gemm_body(
    const float* __restrict__ A, const float* __restrict__ W,
    const float* __restrict__ bias, float* __restrict__ C,
    int M, int N, int K, int ldc)
{
  __shared__ unsigned short As[GBM * LDT];
  __shared__ unsigned short Ws[GBN * LDT];
  const int tid = threadIdx.x;
  const int row0 = blockIdx.y * GBM, col0 = blockIdx.x * GBN;
  const int lane = tid & 63, w = tid >> 6;
  const int wr = w >> 1, wc = w & 1;
  const int lm = lane & 15, lk8 = (lane >> 4) * 8;

  f32x4 acc[4][4];
#pragma unroll
  for (int i = 0; i < 4; i++)
#pragma unroll
    for (int j = 0; j < 4; j++) acc[i][j] = (f32x4)(0.f);

  const int sr = tid >> 1, skh = (tid & 1) * 16;

  for (int kt = 0; kt < K; kt += GBK) {
    {
      const int ar = row0 + sr;
      const int wrow = col0 + sr;
      unsigned short abuf[16], wbuf[16];
#pragma unroll
      for (int q = 0; q < 4; q++) {
        const int k0 = kt + skh + q * 4;
        float4 av = make_float4(0.f, 0.f, 0.f, 0.f);
        float4 wv = make_float4(0.f, 0.f, 0.f, 0.f);
        if (k0 + 4 <= K) {
          if (ar < M)   av = *(const float4*)(A + (size_t)ar * K + k0);
          if (wrow < N) wv = *(const float4*)(W + (size_t)wrow * K + k0);
        }
        abuf[q*4+0] = f2bf(av.x); abuf[q*4+1] = f2bf(av.y);
        abuf[q*4+2] = f2bf(av.z); abuf[q*4+3] = f2bf(av.w);
        wbuf[q*4+0] = f2bf(wv.x); wbuf[q*4+1] = f2bf(wv.y);
        wbuf[q*4+2] = f2bf(wv.z); wbuf[q*4+3] = f2bf(wv.w);
      }
      __syncthreads();
      *(uint4*)(As + sr * LDT + skh)     = *(uint4*)(abuf);
      *(uint4*)(As + sr * LDT + skh + 8) = *(uint4*)(abuf + 8);
      *(uint4*)(Ws + sr * LDT + skh)     = *(uint4*)(wbuf);
      *(uint4*)(Ws + sr * LDT + skh + 8) = *(uint4*)(wbuf + 8);
      __syncthreads();
    }
    bf16x8 af[4], bf[4];
#pragma unroll
    for (int mi = 0; mi < 4; mi++)
      af[mi] = *(const bf16x8*)(As + (wr * 64 + mi * 16 + lm) * LDT + lk8);
#pragma unroll
    for (int ni = 0; ni < 4; ni++)
      bf[ni] = *(const bf16x8*)(Ws + (wc * 64 + ni * 16 + lm) * LDT + lk8);
#pragma unroll
    for (int mi = 0; mi < 4; mi++)
#pragma unroll
      for (int ni = 0; ni < 4; ni++)
        acc[mi][ni] = __builtin_amdgcn_mfma_f32_16x16x32_bf16(
            af[mi], bf[ni], acc[mi][ni], 0, 0, 0);
  }
#pragma unroll
  for (int mi = 0; mi < 4; mi++) {
#pragma unroll
    for (int reg = 0; reg < 4; reg++) {
      const int row = row0 + wr * 64 + mi * 16 + (lane >> 4) * 4 + reg;
      if (row < M) {
        float* crow = C + (size_t)row * ldc;
#pragma unroll
        for (int ni = 0; ni < 4; ni++) {
          const int col = col0 + wc * 64 + ni * 16 + lm;
          crow[col] = acc[mi][ni][reg] + (bias ? bias[col] : 0.f);
        }
      }
    }
  }
}

__global__ __launch_bounds__(256) void gemm_mfma(
    const float* __restrict__ A, const float* __restrict__ W,
    const float* __restrict__ bias, float* __restrict__ C,
    int M, int N, int K, int ldc)
{
  mfma_gemm_body(A, W, bias, C, M, N, K, ldc);
}

__global__ __launch_bounds__(256) void gemm_mfma_dual(
    const float* __restrict__ A0, const float* __restrict__ W0,
    const float* __restrict__ b0, float* __restrict__ C0,
    const float* __restrict__ A1, const float* __restrict__ W1,
    const float* __restrict__ b1, float* __restrict__ C1,
    int M, int N, int K, int ldc)
{
  if (blockIdx.z == 0) mfma_gemm_body(A0, W0, b0, C0, M, N, K, ldc);
  else                 mfma_gemm_body(A1, W1, b1, C1, M, N, K, ldc);
}

__global__ __launch_bounds__(256) void transpose_x(
    const float* __restrict__ x, float* __restrict__ xt)
{
  const int i = blockIdx.x * 256 + threadIdx.x;
  if (i >= T_ * B_ * FEAT_) return;
  const int f = i % FEAT_;
  const int r = i / FEAT_;
  const int b = r % B_;
  const int t = r / B_;
  xt[i] = x[((long)b * T_ + t) * FEAT_ + f];
}

// ---------------- group-split persistent LSTM ----------------
// grid = 256 WGs. wg = dir*128 + bp*16 + member.
//   group (dir, bp) owns batch {bp*2, bp*2+1}; member owns j in [member*32,+32)
//   i.e. 128 gate-rows; weights in 256 VGPRs/thread.
// k-padding: phys(k) = k + (k>>5)*4  -> stride-128B LDS reads become 2-way.
__global__ __launch_bounds__(256, 1) void lstm_chunk(
    const float* __restrict__ gxF,   // [CH][B][4H] fwd x-gates (+bias)
    const float* __restrict__ gxB,   // [CH][B][4H] bwd (local t = CH-1-ls)
    float* __restrict__ hg0,         // [2][B][H] h for even steps
    float* __restrict__ hg1,         // [2][B][H] h for odd steps
    float* __restrict__ cg,          // [2][B][H] c carry
    float* __restrict__ outb,        // [T][B][2H]
    const float* __restrict__ WhhF, const float* __restrict__ WhhB,
    const int* __restrict__ lengths, int s0, int pbase,
    unsigned* __restrict__ bar)      // [16 groups] x 128B apart, monotonic
{
  __shared__ float h_l[2][576];      // 512 data + 64 pad (k + (k>>5)*4)
  __shared__ float gl[256];          // [row128][2b]
  __shared__ float c_l[64];
  __shared__ int   len_l[2];

  const int wg  = blockIdx.x;
  const int dir = wg >> 7;
  const int bp  = (wg >> 4) & 7;
  const int member = wg & 15;
  const int jbase = member * 32;
  const int gid = wg >> 4;           // 0..15
  const int tid = threadIdx.x;
  const int ks = tid & 15, rr = tid >> 4;

  if (tid < 2) len_l[tid] = lengths[bp * 2 + tid];
  if (tid < 64) {
    const int bl = tid >> 5, jj = tid & 31;
    c_l[tid] = cg[(dir * B_ + bp * 2 + bl) * H_ + jbase + jj];
  }

  // weights -> VGPRs: thread (rr,ks) owns rows rr*8..rr*8+7, k in [ks*32,+32)
  const float* Whh = dir ? WhhB : WhhF;
  float4 wreg[8][8];
#pragma unroll
  for (int q = 0; q < 8; q++) {
    const int row128 = rr * 8 + q;
    const int g = row128 >> 5, j = jbase + (row128 & 31);
    const float* wrow = Whh + (size_t)(g * 512 + j) * 512 + ks * 32;
#pragma unroll
    for (int i = 0; i < 8; i++)
      wreg[q][i] = *(const float4*)(wrow + i * 4);
  }
  __syncthreads();

  unsigned* bcnt = bar + gid * 32;   // 128B per group

  for (int ls = 0; ls < CH_; ls++) {
    const int s = s0 + ls;
    // prefetch this step's x-gates early (wave 0 only; consumed at pointwise)
    float gx0 = 0.f, gx1 = 0.f, gx2 = 0.f, gx3 = 0.f;
    if (tid < 64) {
      const int bl = tid >> 5, jj = tid & 31;
      const int b = bp * 2 + bl;
      const int lt = dir ? (CH_ - 1 - ls) : ls;
      const float* gx = (dir ? gxB : gxF) + ((size_t)lt * B_ + b) * H4_ + jbase + jj;
      gx0 = gx[0]; gx1 = gx[512]; gx2 = gx[1024]; gx3 = gx[1536];
    }
    // gather h (4KB): one coherent dwordx4 per thread
    {
      const float* hsrc = ((s & 1) ? hg1 : hg0) + (dir * B_ + bp * 2) * H_;
      const int base = (tid & 127) * 4;
      const int bl = tid >> 7;
      const float4 hv = coh_load_f4(hsrc + bl * H_ + base);
      *(float4*)&h_l[bl][base + (base >> 5) * 4] = hv;
    }
    __syncthreads();

    // dot: acc[q][bl], q = 8 rows, over k-slice [ks*32, +32)
    float acc[8][2];
#pragma unroll
    for (int q = 0; q < 8; q++) { acc[q][0] = 0.f; acc[q][1] = 0.f; }
#pragma unroll
    for (int i = 0; i < 8; i++) {
      const int kp = ks * 36 + i * 4;   // phys(ks*32 + i*4)
      const float4 h40 = *(const float4*)&h_l[0][kp];
      const float4 h41 = *(const float4*)&h_l[1][kp];
#pragma unroll
      for (int q = 0; q < 8; q++) {
        const float4 w4 = wreg[q][i];
        acc[q][0] = fmaf(w4.x, h40.x, acc[q][0]);
        acc[q][0] = fmaf(w4.y, h40.y, acc[q][0]);
        acc[q][0] = fmaf(w4.z, h40.z, acc[q][0]);
        acc[q][0] = fmaf(w4.w, h40.w, acc[q][0]);
        acc[q][1] = fmaf(w4.x, h41.x, acc[q][1]);
        acc[q][1] = fmaf(w4.y, h41.y, acc[q][1]);
        acc[q][1] = fmaf(w4.z, h41.z, acc[q][1]);
        acc[q][1] = fmaf(w4.w, h41.w, acc[q][1]);
      }
    }
    // reduce over ks (lane low 4 bits)
#pragma unroll
    for (int off = 1; off < 16; off <<= 1)
#pragma unroll
      for (int q = 0; q < 8; q++) {
        acc[q][0] += __shfl_xor(acc[q][0], off);
        acc[q][1] += __shfl_xor(acc[q][1], off);
      }
    if (ks == 0) {
#pragma unroll
      for (int q = 0; q < 8; q++) {
        gl[(rr * 8 + q) * 2 + 0] = acc[q][0];
        gl[(rr * 8 + q) * 2 + 1] = acc[q][1];
      }
    }
    __syncthreads();

    // pointwise (wave 0): 2 b x 32 j
    if (tid < 64) {
      const int bl = tid >> 5, jj = tid & 31;
      const int b = bp * 2 + bl;
      const int t = dir ? (T_ - 1 - s) : s;
      const float gi = gl[(0 * 32 + jj) * 2 + bl] + gx0;
      const float gf = gl[(1 * 32 + jj) * 2 + bl] + gx1;
      const float gc = gl[(2 * 32 + jj) * 2 + bl] + gx2;
      const float go = gl[(3 * 32 + jj) * 2 + bl] + gx3;
      const float iv = 1.f / (1.f + expf(-gi));
      const float fv = 1.f / (1.f + expf(-gf));
      const float gv = tanhf(gc);
      const float ov = 1.f / (1.f + expf(-go));
      const float c_old = c_l[tid];
      const int kb = jbase + jj;
      const float h_old = h_l[bl][kb + (kb >> 5) * 4];
      const float cn = fv * c_old + iv * gv;
      const float hn = ov * tanhf(cn);
      const bool mk = t < len_l[bl];
      c_l[tid] = mk ? cn : c_old;
      float* hdst = ((s & 1) ? hg0 : hg1) + (dir * B_ + b) * H_;
      coh_store_f32(&hdst[jbase + jj], mk ? hn : h_old);
      outb[((size_t)t * B_ + b) * H2_ + dir * H_ + jbase + jj] = mk ? hn : 0.f;

      if (ls != CH_ - 1 && tid == 0) {
        // all wave-0 h stores acked at coherence point, then arrive
        asm volatile("s_waitcnt vmcnt(0)" ::: "memory");
        __hip_atomic_fetch_add(bcnt, 1u, __ATOMIC_RELAXED,
                               __HIP_MEMORY_SCOPE_AGENT);
        const unsigned tgt = (unsigned)(pbase + ls + 1) * 16u;
        long tries = 0;
        while (__hip_atomic_load(bcnt, __ATOMIC_RELAXED,
                                 __HIP_MEMORY_SCOPE_AGENT) < tgt) {
          __builtin_amdgcn_s_sleep(1);
          if (++tries > (3L << 21)) break;  // fail loud, never hang
        }
      }
    }
    __syncthreads();
  }
  // carry c to next chunk (kernel boundary publishes)
  if (tid < 64) {
    const int bl = tid >> 5, jj = tid & 31;
    cg[(dir * B_ + bp * 2 + bl) * H_ + jbase + jj] = c_l[tid];
  }
}

// ---------------- decoder kernels (unchanged) ----------------
template <int ACT>
__global__ __launch_bounds__(256) void dotbn(
    const float* __restrict__ S1, const float* __restrict__ W1, int K1,
    const float* __restrict__ S2, const float* __restrict__ W2, int K2,
    const float* __restrict__ pre, int preStride,
    const float* __restrict__ bias,
    float* __restrict__ outp, int outStride, int N)
{
  const int idx = blockIdx.x * 256 + threadIdx.x;
  if (idx >= N * B_) return;
  const int b = idx & 15, n = idx >> 4;
  float acc = bias ? bias[n] : 0.f;
  if (pre) acc += pre[(long)b * preStride + n];
  {
    const float* s = S1 + (long)b * K1;
    const float* w = W1 + (long)n * K1;
#pragma unroll 4
    for (int k = 0; k < K1; k += 4) {
      float4 sv = *(const float4*)(s + k);
      float4 wv = *(const float4*)(w + k);
      acc = fmaf(sv.x, wv.x, acc); acc = fmaf(sv.y, wv.y, acc);
      acc = fmaf(sv.z, wv.z, acc); acc = fmaf(sv.w, wv.w, acc);
    }
  }
  if (S2) {
    const float* s = S2 + (long)b * K2;
    const float* w = W2 + (long)n * K2;
#pragma unroll 4
    for (int k = 0; k < K2; k += 4) {
      float4 sv = *(const float4*)(s + k);
      float4 wv = *(const float4*)(w + k);
      acc = fmaf(sv.x, wv.x, acc); acc = fmaf(sv.y, wv.y, acc);
      acc = fmaf(sv.z, wv.z, acc); acc = fmaf(sv.w, wv.w, acc);
    }
  }
  if (ACT == 1) acc = tanhf(acc);
  outp[(long)b * outStride + n] = acc;
}

__global__ __launch_bounds__(256) void dec_conv(
    const float* __restrict__ alpha, const float* __restrict__ cw,
    float* __restrict__ conv)
{
  const int idx = blockIdx.x * 256 + threadIdx.x;
  if (idx >= B_ * 10 * T_) return;
  const int t = idx % T_;
  const int f = (idx / T_) % 10;
  const int b = idx / (10 * T_);
  const float* a = alpha + b * T_;
  const float* w = cw + f * 100;
  float acc = 0.f;
  const int k0 = (50 - t) > 0 ? (50 - t) : 0;
  const int k1 = (T_ + 50 - t) < 100 ? (T_ + 50 - t) : 100;
  for (int k = k0; k < k1; k++) acc = fmaf(a[t + k - 50], w[k], acc);
  conv[idx] = acc;
}

__global__ __launch_bounds__(256) void att_e(
    const float* __restrict__ se, const float* __restrict__ he,
    const float* __restrict__ conv, const float* __restrict__ W_fe,
    const float* __restrict__ W_ee, float* __restrict__ e)
{
  __shared__ float wfe[10240];
  __shared__ float ses[1024];
  __shared__ float wee[1024];
  __shared__ float red[4];
  const int wg = blockIdx.x;
  const int b = wg / 50, t0 = (wg % 50) * 16;
  const int tid = threadIdx.x;
  for (int i = tid; i < 10240; i += 256) wfe[i] = W_fe[i];
  for (int i = tid; i < 1024; i += 256) {
    ses[i] = se[b * H2_ + i];
    wee[i] = W_ee[i];
  }
  __syncthreads();
  for (int tt = 0; tt < 16; tt++) {
    const int t = t0 + tt;
    float cv[10];
#pragma unroll
    for (int f = 0; f < 10; f++) cv[f] = conv[(b * 10 + f) * T_ + t];
    const float* hrow = he + ((long)t * B_ + b) * H2_;
    float part = 0.f;
#pragma unroll
    for (int q = 0; q < 4; q++) {
      const int d = tid + q * 256;
      float loc = 0.f;
      const float* wf = &wfe[d * 10];
#pragma unroll
      for (int f = 0; f < 10; f++) loc = fmaf(cv[f], wf[f], loc);
      const float val = tanhf(ses[d] + hrow[d] + loc);
      part = fmaf(val, wee[d], part);
    }
#pragma unroll
    for (int off = 32; off; off >>= 1) part += __shfl_down(part, off);
    if ((tid & 63) == 0) red[tid >> 6] = part;
    __syncthreads();
    if (tid == 0) e[b * T_ + t] = red[0] + red[1] + red[2] + red[3];
    __syncthreads();
  }
}

__global__ __launch_bounds__(256) void att_softmax(
    const float* __restrict__ e, const int* __restrict__ lengths,
    float* __restrict__ alpha)
{
  __shared__ float red[4];
  __shared__ float bc, bc2;
  const int b = blockIdx.x, tid = threadIdx.x;
  const int len = lengths[b];
  float v[4];
  float mx = -1e30f;
#pragma unroll
  for (int q = 0; q < 4; q++) {
    const int t = tid + q * 256;
    v[q] = (t < T_) ? e[b * T_ + t] : -1e30f;
    mx = fmaxf(mx, v[q]);
  }
#pragma unroll
  for (int off = 32; off; off >>= 1) mx = fmaxf(mx, __shfl_down(mx, off));
  if ((tid & 63) == 0) red[tid >> 6] = mx;
  __syncthreads();
  if (tid == 0) bc = fmaxf(fmaxf(red[0], red[1]), fmaxf(red[2], red[3]));
  __syncthreads();
  const float m = bc;
  float ex[4];
  float s = 0.f;
#pragma unroll
  for (int q = 0; q < 4; q++) {
    const int t = tid + q * 256;
    ex[q] = (t < T_ && t < len) ? expf(v[q] - m) : 0.f;
    s += ex[q];
  }
#pragma unroll
  for (int off = 32; off; off >>= 1) s += __shfl_down(s, off);
  __syncthreads();
  if ((tid & 63) == 0) red[tid >> 6] = s;
  __syncthreads();
  if (tid == 0) bc2 = red[0] + red[1] + red[2] + red[3];
  __syncthreads();
  const float inv = 1.f / bc2;
#pragma unroll
  for (int q = 0; q < 4; q++) {
    const int t = tid + q * 256;
    if (t < T_) alpha[b * T_ + t] = ex[q] * inv;
  }
}

__global__ __launch_bounds__(256) void att_g(
    const float* __restrict__ alpha, const float* __restrict__ hb,
    float* __restrict__ g)
{
  const int idx = blockIdx.x * 256 + threadIdx.x;
  const int d = idx & (H2_ - 1), b = idx >> 10;
  const float* ab = alpha + b * T_;
  float acc = 0.f;
#pragma unroll 8
  for (int t = 0; t < T_; t++)
    acc = fmaf(ab[t], hb[((long)t * B_ + b) * H2_ + d], acc);
  g[idx] = acc;
}

__global__ __launch_bounds__(256) void dec_update(
    const float* __restrict__ rec, float* __restrict__ s, float* __restrict__ c)
{
  const int idx = blockIdx.x * 256 + threadIdx.x;
  if (idx >= B_ * H_) return;
  const int jj = idx & 511, b = idx >> 9;
  const float* r = rec + b * H4_;
  const float gi = r[jj], gf = r[jj + 512], gc = r[jj + 1024], go = r[jj + 1536];
  const float iv = tanhf(gi * 0.5f) * 0.5f + 0.5f;
  const float fv = tanhf(gf * 0.5f) * 0.5f + 0.5f;
  const float cg = tanhf(gc);
  const float ov = tanhf(go * 0.5f) * 0.5f + 0.5f;
  const float cn = fv * c[idx] + iv * cg;
  const float sn = ov * tanhf(cn);
  c[idx] = cn;
  s[idx] = sn;
}

extern "C" void kernel_launch(void* const* d_in, const int* in_sizes, int n_in,
                              void* d_out, int out_size, void* d_ws, size_t ws_size,
                              hipStream_t stream)
{
  const float* x       = (const float*)d_in[0];
  const int*   lengths = (const int*)  d_in[1];
  const float* target  = (const float*)d_in[2];
  const float* Wih0    = (const float*)d_in[3];
  const float* Whh0    = (const float*)d_in[4];
  const float* b0      = (const float*)d_in[5];
  const float* WihL    = (const float*)d_in[6];
  const float* WhhL    = (const float*)d_in[7];
  const float* bL      = (const float*)d_in[8];
  const float* W_se    = (const float*)d_in[9];
  const float* W_he    = (const float*)d_in[10];
  const float* b_he    = (const float*)d_in[11];
  const float* W_ee    = (const float*)d_in[12];
  const float* conv_w  = (const float*)d_in[13];
  const float* W_fe    = (const float*)d_in[14];
  const float* W_sy    = (const float*)d_in[15];
  const float* W_gy    = (const float*)d_in[16];
  const float* b_gy    = (const float*)d_in[17];
  const float* W_yy    = (const float*)d_in[18];
  const float* b_yy    = (const float*)d_in[19];
  const float* W_ys    = (const float*)d_in[20];
  const float* W_ss    = (const float*)d_in[21];
  const float* W_gs    = (const float*)d_in[22];
  const float* b_gs    = (const float*)d_in[23];
  float* out = (float*)d_out;

  // ---- workspace layout (~119.3 MB) ----
  float* bufA = (float*)d_ws;
  float* bufB = bufA + (size_t)T_ * B_ * H2_;
  float* gxc  = bufB + (size_t)T_ * B_ * H2_;
  float* gxcF = gxc;
  float* gxcB = gxc + (size_t)CH_ * B_ * H4_;
  float* he   = bufB;
  float* ysp  = gxc;
  float* st   = gxc + (size_t)2 * CH_ * B_ * H4_;
  float* hg0  = st;
  float* hg1  = hg0 + 2 * B_ * H_;
  float* cg   = hg1 + 2 * B_ * H_;
  float* sdec = cg + 2 * B_ * H_;
  float* cdec = sdec + B_ * H_;
  float* alpha= cdec + B_ * H_;
  float* conv = alpha + B_ * T_;
  float* ebuf = conv + B_ * 10 * T_;
  float* sebuf= ebuf + B_ * T_;
  float* gvec = sebuf + B_ * H2_;
  float* zvec = gvec + B_ * H2_;
  float* rec  = zvec + B_ * H_;
  unsigned* bar = (unsigned*)(rec + B_ * H4_ + 32);  // 16 groups x 128B

  (void)hipMemsetAsync(bar, 0, 2048, stream);  // once; monotonic thereafter

  // ---- encoder ----
  transpose_x<<<(T_ * B_ * FEAT_ + 255) / 256, 256, 0, stream>>>(x, bufA);

  float* inb  = bufA;
  float* outb = bufB;
  for (int l = 0; l < 4; l++) {
    const int Kin = (l == 0) ? FEAT_ : H2_;
    const float *WihF, *WihB, *WhhF, *WhhB, *bF, *bB;
    if (l == 0) {
      WihF = Wih0;                 WihB = Wih0 + (size_t)H4_ * FEAT_;
      WhhF = Whh0;                 WhhB = Whh0 + (size_t)H4_ * H_;
      bF = b0;                     bB = b0 + H4_;
    } else {
      const size_t o = (size_t)(l - 1) * 2;
      WihF = WihL + o * H4_ * H2_; WihB = WihF + (size_t)H4_ * H2_;
      WhhF = WhhL + o * H4_ * H_;  WhhB = WhhF + (size_t)H4_ * H_;
      bF = bL + o * H4_;           bB = bF + H4_;
    }
    (void)hipMemsetAsync(hg0, 0, (size_t)3 * 2 * B_ * H_ * sizeof(float), stream);
    dim3 gg(H4_ / GBN, (CH_ * B_ + GBM - 1) / GBM, 2);  // (16, 7, 2)
    for (int c = 0; c < T_ / CH_; c++) {
      const int s0 = c * CH_;
      gemm_mfma_dual<<<gg, 256, 0, stream>>>(
          inb + (size_t)s0 * B_ * Kin, WihF, bF, gxcF,
          inb + (size_t)(T_ - s0 - CH_) * B_ * Kin, WihB, bB, gxcB,
          CH_ * B_, H4_, Kin, H4_);
      const int pbase = (l * (T_ / CH_) + c) * (CH_ - 1);
      lstm_chunk<<<256, 256, 0, stream>>>(gxcF, gxcB, hg0, hg1, cg, outb,
                                          WhhF, WhhB, lengths, s0, pbase, bar);
    }
    float* tmp = inb; inb = outb; outb = tmp;
  }
  float* hb = inb;  // final encoder output = bufA

  // ---- decoder precompute (bf16 MFMA) ----
  {
    dim3 ghe(H2_ / GBN, (T_ * B_) / GBM);
    gemm_mfma<<<ghe, 256, 0, stream>>>(hb, W_he, b_he, he, T_ * B_, H2_, H2_, H2_);
    dim3 gys(H4_ / GBN, (B_ * NL_ + GBM - 1) / GBM);
    gemm_mfma<<<gys, 256, 0, stream>>>(target, W_ys, b_gs, ysp, B_ * NL_, H4_, CC_, H4_);
  }
  (void)hipMemsetAsync(sdec, 0, (size_t)(2 * B_ * H_ + B_ * T_) * sizeof(float), stream);

  // ---- decoder steps ----
  for (int step = 0; step < NL_; step++) {
    dec_conv<<<(B_ * 10 * T_ + 255) / 256, 256, 0, stream>>>(alpha, conv_w, conv);
    dotbn<0><<<(B_ * H2_) / 256, 256, 0, stream>>>(
        sdec, W_se, H_, nullptr, nullptr, 0, nullptr, 0, nullptr, sebuf, H2_, H2_);
    att_e<<<800, 256, 0, stream>>>(sebuf, he, conv, W_fe, W_ee, ebuf);
    att_softmax<<<B_, 256, 0, stream>>>(ebuf, lengths, alpha);
    att_g<<<(B_ * H2_) / 256, 256, 0, stream>>>(alpha, hb, gvec);
    dotbn<1><<<(B_ * H_) / 256, 256, 0, stream>>>(
        gvec, W_gy, H2_, sdec, W_sy, H_, nullptr, 0, b_gy, zvec, H_, H_);
    dotbn<0><<<(B_ * CC_ + 255) / 256, 256, 0, stream>>>(
        zvec, W_yy, H_, nullptr, nullptr, 0, nullptr, 0, b_yy,
        out + (size_t)step * CC_, NL_ * CC_, CC_);
    dotbn<0><<<(B_ * H4_) / 256, 256, 0, stream>>>(
        sdec, W_ss, H_, gvec, W_gs, H2_, ysp + (size_t)step * H4_, NL_ * H4_,
        nullptr, rec, H4_, H4_);
    dec_update<<<(B_ * H_) / 256, 256, 0, stream>>>(rec, sdec, cdec);
  }
}